// Round 2
// baseline (305.000 us; speedup 1.0000x reference)
//
#include <hip/hip_runtime.h>

#define D      8192
#define K      1024
#define BLOCK  256
#define GRID_MAX 2048
#define SCALE  0.011048543456039806f   // 1/sqrt(8192)

typedef float nat_f4 __attribute__((ext_vector_type(4)));  // native vec for nontemporal builtin

// Swizzle at float4 granularity: phys4 = f ^ ((f>>3)&7).
// Verified: all phase reads (contiguous-32-per-thread as 8x b128) and all
// transposed writes (stride-256 b32) land <=2 lanes/bank (free per m136).
__device__ __forceinline__ int swz4(int f) { return f ^ ((f >> 3) & 7); }

__device__ __forceinline__ void fwht32(float* x) {
#pragma unroll
    for (int s = 0; s < 5; ++s) {
        const int h = 1 << s;
#pragma unroll
        for (int g = 0; g < 32; g += 2 * h)
#pragma unroll
            for (int e = 0; e < h; ++e) {
                float a = x[g + e], b = x[g + e + h];
                x[g + e]     = a + b;
                x[g + e + h] = a - b;
            }
    }
}

__device__ __forceinline__ void fwht8(float* x) {
#pragma unroll
    for (int s = 0; s < 3; ++s) {
        const int h = 1 << s;
#pragma unroll
        for (int g = 0; g < 8; g += 2 * h)
#pragma unroll
            for (int e = 0; e < h; ++e) {
                float a = x[g + e], b = x[g + e + h];
                x[g + e]     = a + b;
                x[g + e + h] = a - b;
            }
    }
}

// Bit bookkeeping (orig index i = b12..b0):
//  L0 (post-scatter) = i.            P1 thread t: reads words [t*32,t*32+32)
//     -> transforms b0..b4, writes x[j] to L1 = (j<<8)|t.
//  L1 bits 0..7 = b5..b12, bits 8..12 = b0..b4.   P2 thread t: reads
//     [t*32,..) -> transforms b5..b9, writes to L2 = (m<<8)|t.
//  L2 bits: k=L2&31 -> (b10,b11,b12,b0,b1); t2=L2>>5 -> (b2..b4, b5..b9).
//     P3: 4x fwht8 over k&7 (=b10..b12), then float4 store:
//     i = g | (t&7)<<2 | (t>>3)<<5 | e<<10,  g = k>>3, e = k&7.
//
// This version: persistent row-looped blocks (grid-stride). Row n's global
// stores overlap row n+1's zero/scatter/FWHT (stores never gate LDS reuse);
// idx is loaded once per block; next row's u-float4 is prefetched right
// after the scatter consumes the current one.
__global__ __launch_bounds__(BLOCK, 5)
void UpProjectFastHadamardTransform_80101140070867_kernel(
    const float* __restrict__ u, const int* __restrict__ idx,
    float* __restrict__ out, int nrows)
{
    __shared__ float4 lds4[D / 4];
    float* lds = (float*)lds4;
    const int t = threadIdx.x;

    const int4 id = ((const int4*)idx)[t];             // once per block
    const int c  = t & 7;                                     // swz4 xor for f=t*8+g
    const int wb = 4 * ((t >> 2) ^ ((t >> 5) & 7)) + (t & 3); // transposed-write base

    int r = blockIdx.x;                                // grid <= nrows always
    float4 v = ((const float4*)(u + (size_t)r * K))[t];

    for (; r < nrows; ) {
        // prev-iter P3 LDS reads must complete before zero-fill (no-op on iter 0)
        __syncthreads();

        // zero LDS (physical-linear float4: swizzle-agnostic, conflict-free)
#pragma unroll
        for (int j = 0; j < D / 4 / BLOCK; ++j)
            lds4[t + j * BLOCK] = make_float4(0.f, 0.f, 0.f, 0.f);
        __syncthreads();

        // scatter-add (duplicate idx accumulate); logical word w -> phys word
        {
            int f, a;
            f = id.x >> 2; a = 4 * swz4(f) + (id.x & 3); atomicAdd(&lds[a], v.x);
            f = id.y >> 2; a = 4 * swz4(f) + (id.y & 3); atomicAdd(&lds[a], v.y);
            f = id.z >> 2; a = 4 * swz4(f) + (id.z & 3); atomicAdd(&lds[a], v.z);
            f = id.w >> 2; a = 4 * swz4(f) + (id.w & 3); atomicAdd(&lds[a], v.w);
        }

        // prefetch next row's u (uniform branch; ~full row of latency cover)
        const int rn = r + (int)gridDim.x;
        if (rn < nrows) v = ((const float4*)(u + (size_t)rn * K))[t];
        __syncthreads();

        float x[32];

        // ---- Phase 1: bits 0-4 ----
#pragma unroll
        for (int g = 0; g < 8; ++g) {
            float4 a = lds4[t * 8 + (g ^ c)];
            x[4*g+0] = a.x; x[4*g+1] = a.y; x[4*g+2] = a.z; x[4*g+3] = a.w;
        }
        fwht32(x);
        __syncthreads();                         // all reads done before overwrite
#pragma unroll
        for (int j = 0; j < 32; ++j) lds[j * 256 + wb] = x[j];  // -> L1 (transposed)
        __syncthreads();

        // ---- Phase 2: bits 5-9 ----
#pragma unroll
        for (int g = 0; g < 8; ++g) {
            float4 a = lds4[t * 8 + (g ^ c)];
            x[4*g+0] = a.x; x[4*g+1] = a.y; x[4*g+2] = a.z; x[4*g+3] = a.w;
        }
        fwht32(x);
        __syncthreads();
#pragma unroll
        for (int j = 0; j < 32; ++j) lds[j * 256 + wb] = x[j];  // -> L2 (transposed)
        __syncthreads();

        // ---- Phase 3: bits 10-12, fused with store ----
#pragma unroll
        for (int g = 0; g < 8; ++g) {
            float4 a = lds4[t * 8 + (g ^ c)];
            x[4*g+0] = a.x; x[4*g+1] = a.y; x[4*g+2] = a.z; x[4*g+3] = a.w;
        }
#pragma unroll
        for (int g2 = 0; g2 < 4; ++g2) fwht8(&x[g2 * 8]);

        float* orow = out + (size_t)r * D + ((t >> 3) * 32 + (t & 7) * 4);
#pragma unroll
        for (int e = 0; e < 8; ++e) {
            nat_f4 o = { x[e] * SCALE, x[8 + e] * SCALE,
                         x[16 + e] * SCALE, x[24 + e] * SCALE };
            // streaming 256 MiB output: don't allocate in L2
            __builtin_nontemporal_store(o, (nat_f4*)(orow + e * 1024));
        }

        r = rn;
    }
}

extern "C" void kernel_launch(void* const* d_in, const int* in_sizes, int n_in,
                              void* d_out, int out_size, void* d_ws, size_t ws_size,
                              hipStream_t stream) {
    const float* u   = (const float*)d_in[0];
    const int*   idx = (const int*)d_in[1];
    float*       out = (float*)d_out;
    const int rows = in_sizes[0] / K;   // 8192
    const int grid = rows < GRID_MAX ? rows : GRID_MAX;   // 2048 -> 4 rows/block
    hipLaunchKernelGGL(UpProjectFastHadamardTransform_80101140070867_kernel,
                       dim3(grid), dim3(BLOCK), 0, stream, u, idx, out, rows);
}